// Round 6
// baseline (584.415 us; speedup 1.0000x reference)
//
#include <hip/hip_runtime.h>

// MoE fused kernel, MI355X gfx950 — Round 9: LDS-traffic cut via row-split +
// register A-reuse. Shapes: B=65536, D=512, C=101, E=8, H=256.
// out[b,c] = sum_{e,h} g[b,e]*relu(x@W1+b1)[b,e,h]*W2[e,h,c] + sum_e g[b,e]*b2[e,c]
// g = softmax(x@Wg+bg), gate logits folded into layer1 GEMM as cols 2048..2055.
//
// R8 post-mortem: Mtile 32->64 halved L2 weight traffic AND halved waves/CU;
// dur 264->257 (-3%), MfmaUtil 28.4 both. Kills the L2-BW theory. Invariant
// between R7/R8: per-CU LDS traffic (layer1 a-reads 512KB/CU/expert, layer2
// hA 448KB/CU/it in both) — the column-split multiplies A re-reads from LDS,
// and at 2 waves/SIMD the ds_read->MFMA chain is exposed. R9 keeps R8's
// geometry (Mtile=64, 512 thr, 130KB LDS, 1 blk/CU, ct-owned acc2, 8 in-loop
// barriers) but re-grids:
//   layer1: 2-row x 4-col waves, acc1[2][4] — 2 a-reads/kf reused x4 ->
//           A-LDS 256KB/CU/expert (was 512). B-frags shared by 2 waves -> L1.
//   layer2: 4-row x 2-col waves, acc2[4] (ct-owned, full K, no reduction) —
//           each wave reads only its row-quarter of hA: 128KB/CU/it (was 448).
// Per-expert LDS ~350KB/CU (was ~770) < MFMA pipe time (~5000cyc) -> MFMA
// becomes the binding pipe. Regs ~150 under launch_bounds(512,2) cap 256.
// (SQ_LDS_BANK_CONFLICT=7905280 every round regardless of kernel — artifact,
// ignored.)
//
// MFMA layouts (m89/m120-verified):
//   A: A[m][k], m=lane&15, k=(lane>>4)*8+j (j=0..7)
//   B: B[k][n], n=lane&15, k=(lane>>4)*8+j
//   C/D: col=lane&15, row=(lane>>4)*4+reg

typedef __attribute__((ext_vector_type(8))) short short8x;
typedef __attribute__((ext_vector_type(4))) float float4x;

#define C_DIM 101

__device__ __forceinline__ unsigned short f2bf(float f) {
  unsigned int u = __builtin_bit_cast(unsigned int, f);
  u += 0x7fffu + ((u >> 16) & 1u);     // round-to-nearest-even
  return (unsigned short)(u >> 16);
}

// ---- merged weight conversion (one launch)
// W1 (+Wg) -> bf16 B-frags: frag = ntile*16+kf ; elem = frag*512 + lane*8 + j
// W2       -> bf16 B-frags: frag = ntile*64+kf ; ntile 0..7, kf 0..63 (K=2048)
__global__ void conv_weights(const float* __restrict__ W1, const float* __restrict__ Wg,
                             const float* __restrict__ W2,
                             unsigned short* __restrict__ W1bf,
                             unsigned short* __restrict__ W2bf) {
  if (blockIdx.x < 516) {
    int s = blockIdx.x * blockDim.x + threadIdx.x;   // slot = frag*64 + lane
    int l = s & 63;
    int frag = s >> 6;
    int kf = frag & 15;
    int ntile = frag >> 4;
    int n = (ntile << 4) | (l & 15);
    int k = (kf << 5) | ((l >> 4) << 3);
    short8x v;
#pragma unroll
    for (int j = 0; j < 8; ++j) {
      int kk = k + j;
      float f;
      if (n < 2048)      f = W1[((size_t)(n >> 8) * 512 + kk) * 256 + (n & 255)];
      else if (n < 2056) f = Wg[(size_t)kk * 8 + (n - 2048)];
      else               f = 0.f;
      v[j] = (short)f2bf(f);
    }
    *(short8x*)(W1bf + (size_t)s * 8) = v;
  } else {
    int s = (blockIdx.x - 516) * blockDim.x + threadIdx.x;
    int l = s & 63;
    int frag = s >> 6;
    int kf = frag & 63;
    int ntile = frag >> 6;
    int c = (ntile << 4) | (l & 15);
    int k = (kf << 5) | ((l >> 4) << 3);
    short8x v;
#pragma unroll
    for (int j = 0; j < 8; ++j) {
      int kk = k + j;                       // e = kk>>8, h = kk&255
      float f = (c < C_DIM) ? W2[((size_t)(kk >> 8) * 256 + (kk & 255)) * C_DIM + c] : 0.f;
      v[j] = (short)f2bf(f);
    }
    *(short8x*)(W2bf + (size_t)s * 8) = v;
  }
}

// ---- fused main kernel: 64 rows/block, 512 threads (8 waves), 1 block/CU
__global__ __launch_bounds__(512, 2) void moe_main(
    const float* __restrict__ x, const float* __restrict__ b1,
    const float* __restrict__ b2, const float* __restrict__ bg,
    const unsigned short* __restrict__ W1bf, const unsigned short* __restrict__ W2bf,
    float* __restrict__ out) {
  __shared__ unsigned short xA[64 * 512];   // 64 KB: x A-frags [mt*16+kf][lane*8+j]
  __shared__ unsigned short hA[64 * 512];   // 64 KB: 2 experts x 32 h' A-frags
  __shared__ float gt[8 * 64];              //  2 KB: gates^T [e][row]
  float* graw = (float*)hA;                 // raw gate logits [64][8]; pre-loop only

  const int tid = threadIdx.x;
  const int w = tid >> 6;     // wave 0..7
  const int l = tid & 63;     // lane
  const int quad = l >> 4;
  const int p = l & 15;
  const int r0 = blockIdx.x * 64;
  // layer1 wave grid: rh = row half (0..1), cq = col quarter (0..3)
  const int rh = w >> 2;
  const int cq = w & 3;
  // layer2 wave grid: mt_own = row quarter (0..3), cg = col group (0..1)
  const int mt_own = w >> 1;
  const int cg = w & 1;

  // ---- stage x -> bf16 A-frag LDS (coalesced float4 x2 reads, b128 LDS writes)
#pragma unroll
  for (int it = 0; it < 8; ++it) {
    int g = tid + it * 512;            // m = g>>6 (0..63), k0 = (g&63)*8
    int m = g >> 6;
    int k0 = (g & 63) << 3;
    const float* src = x + (size_t)(r0 + m) * 512 + k0;
    float4 f0 = *(const float4*)src;
    float4 f1 = *(const float4*)(src + 4);
    short8x v;
    v[0] = (short)f2bf(f0.x); v[1] = (short)f2bf(f0.y);
    v[2] = (short)f2bf(f0.z); v[3] = (short)f2bf(f0.w);
    v[4] = (short)f2bf(f1.x); v[5] = (short)f2bf(f1.y);
    v[6] = (short)f2bf(f1.z); v[7] = (short)f2bf(f1.w);
    int mt = m >> 4;
    int kfrag = k0 >> 5;
    int lane = (((k0 >> 3) & 3) << 4) | (m & 15);
    *(short8x*)&xA[(size_t)(((mt << 4) | kfrag) * 64 + lane) * 8] = v;
  }
  __syncthreads();

  // ---- gate logits: waves 0..3 each do one 16-row tile x 16 gate cols (ntile 128)
  if (w < 4) {
    float4x acc = {0.f, 0.f, 0.f, 0.f};
#pragma unroll 2
    for (int kf = 0; kf < 16; ++kf) {
      short8x a = *(const short8x*)&xA[(size_t)((w * 16 + kf) * 64 + l) * 8];
      short8x b = *(const short8x*)(W1bf + ((size_t)(128 * 16 + kf) * 512 + l * 8));
      acc = __builtin_amdgcn_mfma_f32_16x16x32_bf16(a, b, acc, 0, 0, 0);
    }
    if (p < 8) {
      float bgv = bg[p];
#pragma unroll
      for (int r = 0; r < 4; ++r)
        graw[(w * 16 + quad * 4 + r) * 8 + p] = acc[r] + bgv;
    }
  }
  __syncthreads();
  // softmax over E=8 per row, fp32; write transposed gt[e][row]
  if (tid < 64) {
    float v[8], mx = -1e30f;
#pragma unroll
    for (int e = 0; e < 8; ++e) { v[e] = graw[tid * 8 + e]; mx = fmaxf(mx, v[e]); }
    float s = 0.f;
#pragma unroll
    for (int e = 0; e < 8; ++e) { v[e] = expf(v[e] - mx); s += v[e]; }
    float inv = 1.f / s;
#pragma unroll
    for (int e = 0; e < 8; ++e) gt[e * 64 + tid] = v[e] * inv;
  }
  __syncthreads();   // graw (hA alias) reads done before first hA write

  // ---- main loop: 4 iterations, 2 experts each.
  float4x zero = {0.f, 0.f, 0.f, 0.f};
  float4x acc2[4];                       // [ct2]; wave owns rows mt_own*16, ct = cg*4+ct2
  acc2[0] = zero; acc2[1] = zero; acc2[2] = zero; acc2[3] = zero;

  for (int it = 0; it < 4; ++it) {
#pragma unroll
    for (int eo = 0; eo < 2; ++eo) {
      const int e = it * 2 + eo;
      // layer1: wave (rh,cq) = rows [rh*32,+32) x h-cols [e*256 + cq*64, +64)
      float4x acc1[2][4];                // [mtl][nc]
#pragma unroll
      for (int mtl = 0; mtl < 2; ++mtl)
#pragma unroll
        for (int nc = 0; nc < 4; ++nc) acc1[mtl][nc] = zero;

      const unsigned short* __restrict__ bp =
          W1bf + ((size_t)(e * 16 + cq * 4) * 16) * 512 + (size_t)l * 8;
      // nc stride = 16 frags * 512 = 8192 shorts; kf stride = 512 shorts
      short8x bA[4], bB[4];
#pragma unroll
      for (int nc = 0; nc < 4; ++nc) bA[nc] = *(const short8x*)(bp + nc * 8192);

#pragma unroll
      for (int kf = 0; kf < 16; kf += 2) {
#pragma unroll
        for (int nc = 0; nc < 4; ++nc)
          bB[nc] = *(const short8x*)(bp + nc * 8192 + (kf + 1) * 512);
        short8x a0 = *(const short8x*)&xA[(size_t)(((rh * 2 + 0) * 16 + kf) * 64 + l) * 8];
        short8x a1 = *(const short8x*)&xA[(size_t)(((rh * 2 + 1) * 16 + kf) * 64 + l) * 8];
#pragma unroll
        for (int nc = 0; nc < 4; ++nc) {
          acc1[0][nc] = __builtin_amdgcn_mfma_f32_16x16x32_bf16(a0, bA[nc], acc1[0][nc], 0, 0, 0);
          acc1[1][nc] = __builtin_amdgcn_mfma_f32_16x16x32_bf16(a1, bA[nc], acc1[1][nc], 0, 0, 0);
        }
        if (kf + 2 < 16) {
#pragma unroll
          for (int nc = 0; nc < 4; ++nc)
            bA[nc] = *(const short8x*)(bp + nc * 8192 + (kf + 2) * 512);
        }
        short8x a2 = *(const short8x*)&xA[(size_t)(((rh * 2 + 0) * 16 + kf + 1) * 64 + l) * 8];
        short8x a3 = *(const short8x*)&xA[(size_t)(((rh * 2 + 1) * 16 + kf + 1) * 64 + l) * 8];
#pragma unroll
        for (int nc = 0; nc < 4; ++nc) {
          acc1[0][nc] = __builtin_amdgcn_mfma_f32_16x16x32_bf16(a2, bB[nc], acc1[0][nc], 0, 0, 0);
          acc1[1][nc] = __builtin_amdgcn_mfma_f32_16x16x32_bf16(a3, bB[nc], acc1[1][nc], 0, 0, 0);
        }
      }

      if (eo == 0) __syncthreads();      // BAR1: prev iteration's layer2 hA reads done

      // epilogue: +b1, relu, *gate(e), bf16 -> hA (C->A transpose)
      // h' element (row, hcol): frag = eo*32 + (hcol>>5)*4 + (row>>4);
      //   lane = ((hcol&31)>>3)*16 + (row&15); j = hcol&7
      float4x gv0 = *(const float4x*)&gt[e * 64 + rh * 32 + 0  + quad * 4];
      float4x gv1 = *(const float4x*)&gt[e * 64 + rh * 32 + 16 + quad * 4];
#pragma unroll
      for (int nc = 0; nc < 4; ++nc) {
        int cw = cq * 64 + nc * 16 + p;  // h-col within expert tile (0..255)
        float b1v = b1[e * 256 + cw];
        int kf2g = cw >> 5;              // K-frag 0..7
        int koff = cw & 31;
        int jj = koff & 7;
        int ldbase = (koff >> 3) << 4;
#pragma unroll
        for (int mtl = 0; mtl < 2; ++mtl) {
          int frag = eo * 32 + kf2g * 4 + (rh * 2 + mtl);
          float4x gv = mtl ? gv1 : gv0;
#pragma unroll
          for (int r = 0; r < 4; ++r) {
            float hv = fmaxf(acc1[mtl][nc][r] + b1v, 0.f) * gv[r];
            hA[(size_t)frag * 512 + (ldbase + quad * 4 + r) * 8 + jj] = f2bf(hv);
          }
        }
      }
    }
    __syncthreads();                     // BAR2: both experts' h' published

    // layer2: wave (mt_own,cg) owns rows [mt_own*16,+16) x ct in [cg*4, cg*4+4)
    // reads ONLY its row-quarter of hA: 1 a-frag per (eo,kf2), reused x4 ct
#pragma unroll
    for (int eo = 0; eo < 2; ++eo) {
#pragma unroll
      for (int kf2 = 0; kf2 < 8; ++kf2) {
        short8x a = *(const short8x*)&hA[(size_t)((eo * 32 + kf2 * 4 + mt_own) * 64 + l) * 8];
#pragma unroll
        for (int ct2 = 0; ct2 < 4; ++ct2) {
          int ct = cg * 4 + ct2;
          if (ct < 7) {                  // ct=7 all-padding (C=101)
            short8x b = *(const short8x*)(W2bf +
                ((size_t)(ct * 64 + it * 16 + eo * 8 + kf2)) * 512 + (size_t)l * 8);
            acc2[ct2] = __builtin_amdgcn_mfma_f32_16x16x32_bf16(a, b, acc2[ct2], 0, 0, 0);
          }
        }
      }
    }
  }

  // ---- epilogue: + gate-weighted b2, store. No cross-wave reduction.
#pragma unroll
  for (int ct2 = 0; ct2 < 4; ++ct2) {
    int c = (cg * 4 + ct2) * 16 + p;
    if (c < C_DIM) {
#pragma unroll
      for (int r = 0; r < 4; ++r) {
        int row = mt_own * 16 + quad * 4 + r;
        float bias = 0.f;
#pragma unroll
        for (int e = 0; e < 8; ++e) bias += gt[e * 64 + row] * b2[e * C_DIM + c];
        out[(size_t)(r0 + row) * C_DIM + c] = acc2[ct2][r] + bias;
      }
    }
  }
}

extern "C" void kernel_launch(void* const* d_in, const int* in_sizes, int n_in,
                              void* d_out, int out_size, void* d_ws, size_t ws_size,
                              hipStream_t stream) {
  const float* x  = (const float*)d_in[0];
  const float* W1 = (const float*)d_in[1];
  const float* b1 = (const float*)d_in[2];
  const float* W2 = (const float*)d_in[3];
  const float* b2 = (const float*)d_in[4];
  const float* Wg = (const float*)d_in[5];
  const float* bg = (const float*)d_in[6];
  float* out = (float*)d_out;

  unsigned short* W1bf = (unsigned short*)d_ws;
  unsigned short* W2bf = (unsigned short*)((char*)d_ws + (size_t)129 * 16 * 512 * 2);

  conv_weights<<<644, 256, 0, stream>>>(W1, Wg, W2, W1bf, W2bf);  // 516 + 128 blocks
  moe_main<<<1024, 512, 0, stream>>>(x, b1, b2, bg, W1bf, W2bf, out);
}